// Round 3
// baseline (85.410 us; speedup 1.0000x reference)
//
#include <hip/hip_runtime.h>
#include <math.h>

// Problem constants (from reference): B=8, C=32, F=32, K=3, H=W=32
#define NB 8
#define NC 32
#define NF 32
#define NH 32
#define NW 32
#define NQ 9
#define CSPLIT 4            // channel-loop split factor (8 channels per block)
#define CPB (NC / CSPLIT)   // channels per block
#define TROWS 18            // staged padded rows per half-image (16 + 2 halo)
#define TS 34               // padded tile row stride (W+2)
#define TILE_N (TROWS * TS) // 612

// Block = 256 threads, each owns 2 vertically-adjacent output pixels
// (16 rows x 32 cols = half image). Grid = B*F*2 halves * CSPLIT = 2048
// -> 8 blocks/CU -> 32 waves/CU (8/SIMD). Coefficients are block-uniform ->
// scalar loads; SCALAR fp32 math (v_pk_fma_f32 would force VGPR-pair
// materialization of every SGPR coefficient: ~2 v_mov per coeff per term).
// Channel partials combined with HW fp32 atomics (out pre-zeroed).
__global__ __launch_bounds__(256, 8) void ka_conv_rational_kernel(
    const float* __restrict__ x,     // [B, C, H, W]
    const float* __restrict__ nums,  // [F*Q*C, 6]
    const float* __restrict__ dens,  // [F*Q*C, 4]
    float* __restrict__ out)         // [B, F, H, W]
{
    __shared__ float tile[2][TILE_N];

    const int t    = threadIdx.x;
    const int bid  = blockIdx.x;          // 0..2047
    const int cs   = bid & (CSPLIT - 1);  // channel chunk
    const int half = (bid >> 2) & 1;      // which 16-row half of the image
    const int bf   = bid >> 3;            // = b*NF + f, 0..255
    const int f    = bf & (NF - 1);
    const int bb   = bf >> 5;             // / NF
    const int xx   = t & 31;              // output column
    const int ty   = t >> 5;              // 0..7 -> owns rows 2*ty, 2*ty+1 of the half
    const int c0   = cs * CPB;

    // c-invariant staging geometry: element idx of the 18x34 padded tile.
    // padded row (global) = half*16 + ry  ->  unpadded gy = half*16 + ry - 1
    int  soff[3];
    bool svalid[3];
#pragma unroll
    for (int i = 0; i < 3; ++i) {
        int idx = t + i * 256;
        int ry  = idx / TS;
        int rx  = idx - ry * TS;
        int gy  = half * 16 + ry - 1;
        int gx  = rx - 1;
        bool ok = (idx < TILE_N) && (gy >= 0) && (gy < NH) && (gx >= 0) && (gx < NW);
        svalid[i] = ok;
        soff[i]   = ok ? (gy * NW + gx) : 0; // clamped: always in-bounds
    }

    const float* __restrict__ xb    = x    + ((size_t)bb * NC + c0) * NH * NW;
    const float* __restrict__ abase = nums + (size_t)f * NQ * NC * 6;
    const float* __restrict__ bbase = dens + (size_t)f * NQ * NC * 4;

    // prefetch first channel into registers
    float st[3];
#pragma unroll
    for (int i = 0; i < 3; ++i)
        st[i] = xb[soff[i]];

    float acc0 = 0.f, acc1 = 0.f;

    for (int ci = 0; ci < CPB; ++ci) {
        const int c = c0 + ci;
        float* tl = tile[ci & 1];

        // write staged channel (zero-padded) to LDS
#pragma unroll
        for (int i = 0; i < 3; ++i) {
            int idx = t + i * 256;
            if (idx < TILE_N)
                tl[idx] = svalid[i] ? st[i] : 0.f;
        }
        // prefetch next channel (latency hidden behind compute below)
        if (ci + 1 < CPB) {
            const float* xc = xb + (size_t)(ci + 1) * NH * NW;
#pragma unroll
            for (int i = 0; i < 3; ++i)
                st[i] = xc[soff[i]];
        }
        __syncthreads(); // double-buffered: buffer (ci&1) next rewritten at ci+2

        // 4x3 neighborhood covering both pixels' 3x3 windows
        float n[4][3];
#pragma unroll
        for (int dy = 0; dy < 4; ++dy)
#pragma unroll
            for (int dx = 0; dx < 3; ++dx)
                n[dy][dx] = tl[(ty * 2 + dy) * TS + (xx + dx)];

#pragma unroll
        for (int q = 0; q < NQ; ++q) {
            // block-uniform coefficient loads -> scalar loads (SGPRs)
            const float* ap = abase + (size_t)(q * NC + c) * 6;
            const float* bp = bbase + (size_t)(q * NC + c) * 4;
            const float a0 = ap[0], a1 = ap[1], a2 = ap[2],
                        a3 = ap[3], a4 = ap[4], a5 = ap[5];
            const float d0 = bp[0], d1 = bp[1], d2 = bp[2], d3 = bp[3];
            const int qi = q / 3, qj = q - qi * 3;

            // scalar Horner; both pixels share the same coefficient registers
            {
                const float w  = n[qi][qj];
                float nu = fmaf(fmaf(fmaf(fmaf(fmaf(a5, w, a4), w, a3), w, a2), w, a1), w, a0);
                float dp = fmaf(fmaf(fmaf(d3, w, d2), w, d1), w, d0) * w;
                float de = 1.0f + fabsf(dp);
                acc0 = fmaf(nu, __builtin_amdgcn_rcpf(de), acc0);
            }
            {
                const float w  = n[qi + 1][qj];
                float nu = fmaf(fmaf(fmaf(fmaf(fmaf(a5, w, a4), w, a3), w, a2), w, a1), w, a0);
                float dp = fmaf(fmaf(fmaf(d3, w, d2), w, d1), w, d0) * w;
                float de = 1.0f + fabsf(dp);
                acc1 = fmaf(nu, __builtin_amdgcn_rcpf(de), acc1);
            }
        }
    }

    const int y0 = half * 16 + ty * 2;
    float* op = out + ((size_t)bf * NH + y0) * NW + xx;
    unsafeAtomicAdd(op, acc0);
    unsafeAtomicAdd(op + NW, acc1);
}

extern "C" void kernel_launch(void* const* d_in, const int* in_sizes, int n_in,
                              void* d_out, int out_size, void* d_ws, size_t ws_size,
                              hipStream_t stream) {
    const float* x    = (const float*)d_in[0];
    const float* nums = (const float*)d_in[1];
    const float* dens = (const float*)d_in[2];
    float* out = (float*)d_out;

    // atomic accumulation target must start at zero (harness poisons d_out)
    hipMemsetAsync(d_out, 0, (size_t)out_size * sizeof(float), stream);

    dim3 grid(NB * NF * 2 * CSPLIT); // 2048 blocks: (b, f, half, csplit)
    dim3 block(256);
    ka_conv_rational_kernel<<<grid, block, 0, stream>>>(x, nums, dens, out);
}